// Round 1
// baseline (160.381 us; speedup 1.0000x reference)
//
#include <hip/hip_runtime.h>
#include <cstdint>
#include <cstddef>

typedef unsigned long long u64;

// Problem constants (N,P,T,H,W) = (8,32,16,384,384)
constexpr int N_  = 8;
constexpr int P_  = 32;
constexpr int T_  = 16;
constexpr int HW  = 384 * 384;        // 147456 pixels per mask
constexpr int WORDS = HW / 64;        // 2304 u64 words per mask
constexpr int GPN = HW / 256;         // 576 256-pixel groups per image

// ---------------------------------------------------------------------------
// Pack float {0,1} masks into bits. One wave handles 256 consecutive pixels:
// lane l loads float4 at pixel g*256 + 4l; bit layout: word[g*4+j] bit l =
// pixel (g*256 + 4l + j). Consumers use the identical layout.
// ---------------------------------------------------------------------------
__global__ void pack_kernel(const float* __restrict__ src, u64* __restrict__ dst,
                            int ngroups) {
    int wave   = (blockIdx.x * blockDim.x + threadIdx.x) >> 6;
    int lane   = threadIdx.x & 63;
    int nwaves = (gridDim.x * blockDim.x) >> 6;
    for (int g = wave; g < ngroups; g += nwaves) {
        float4 v = reinterpret_cast<const float4*>(src)[(size_t)g * 64 + lane];
        u64 b0 = __ballot(v.x != 0.0f);
        u64 b1 = __ballot(v.y != 0.0f);
        u64 b2 = __ballot(v.z != 0.0f);
        u64 b3 = __ballot(v.w != 0.0f);
        if (lane == 0) {
            u64* d = dst + (size_t)g * 4;
            d[0] = b0; d[1] = b1; d[2] = b2; d[3] = b3;
        }
    }
}

// Block-wide integer sum reduction (256 threads = 4 waves). Result on all threads.
__device__ inline int block_reduce_sum(int v) {
    __shared__ int buf[4];
    #pragma unroll
    for (int o = 32; o >= 1; o >>= 1) v += __shfl_down(v, o, 64);
    __syncthreads();                       // protect buf from a previous call
    if ((threadIdx.x & 63) == 0) buf[threadIdx.x >> 6] = v;
    __syncthreads();
    return buf[0] + buf[1] + buf[2] + buf[3];
}

// ---------------------------------------------------------------------------
// One 256-thread block per (n,p): holds its 9 pred words in registers, loops
// over t computing popcount(pred & true). Also emits area_p; the p==0 blocks
// additionally emit area_t.
// ---------------------------------------------------------------------------
__global__ void inter_kernel(const u64* __restrict__ pp, const u64* __restrict__ pt,
                             float* __restrict__ inter, float* __restrict__ area_p,
                             float* __restrict__ area_t) {
    const int np = blockIdx.x;            // n*P + p
    const int n  = np >> 5;
    const int p  = np & 31;
    const int tid = threadIdx.x;

    const u64* pw = pp + (size_t)np * WORDS;
    u64 a[9];
    #pragma unroll
    for (int k = 0; k < 9; ++k) a[k] = pw[tid + 256 * k];

    int my_area = 0;
    #pragma unroll
    for (int k = 0; k < 9; ++k) my_area += __popcll(a[k]);
    int ap = block_reduce_sum(my_area);
    if (tid == 0) area_p[np] = (float)ap;

    for (int t = 0; t < T_; ++t) {
        const u64* tw = pt + ((size_t)(n * T_ + t)) * WORDS;
        int s = 0, st = 0;
        #pragma unroll
        for (int k = 0; k < 9; ++k) {
            u64 w = tw[tid + 256 * k];
            s += __popcll(a[k] & w);
            if (p == 0) st += __popcll(w);
        }
        int is = block_reduce_sum(s);
        if (tid == 0) inter[(size_t)np * T_ + t] = (float)is;
        if (p == 0) {                     // block-uniform branch: syncs are safe
            int at = block_reduce_sum(st);
            if (tid == 0) area_t[n * T_ + t] = (float)at;
        }
    }
}

// ---------------------------------------------------------------------------
// iou_max per (n,p). One block, 256 threads (= N*P).
// ---------------------------------------------------------------------------
__global__ void ioumax_kernel(const float* __restrict__ inter,
                              const float* __restrict__ area_p,
                              const float* __restrict__ area_t,
                              float* __restrict__ ioumax) {
    int tid = threadIdx.x;                // tid = n*P + p
    int n = tid >> 5;
    float ap = area_p[tid];
    float best = 0.0f;
    #pragma unroll
    for (int t = 0; t < T_; ++t) {
        float it = inter[(size_t)tid * T_ + t];
        float at = area_t[n * T_ + t];
        float u  = ap + at - it;
        float iou = (u > 0.0f) ? (it / u) : 0.0f;
        best = fmaxf(best, iou);
    }
    ioumax[tid] = best;
}

// ---------------------------------------------------------------------------
// Per-pixel score. One wave per 256-pixel group; lane l owns pixels
// g*256 + 4l + j (j=0..3), i.e. bit l of words [g*4+j] — matching pack layout.
// ---------------------------------------------------------------------------
__global__ void score_kernel(const u64* __restrict__ pp,
                             const float* __restrict__ ioumax,
                             float* __restrict__ out) {
    int wave   = (blockIdx.x * blockDim.x + threadIdx.x) >> 6;
    int lane   = threadIdx.x & 63;
    int nwaves = (gridDim.x * blockDim.x) >> 6;
    const int total_groups = N_ * GPN;    // 4608
    for (int g = wave; g < total_groups; g += nwaves) {
        int n  = g / GPN;
        int gl = g - n * GPN;
        const u64* base = pp + ((size_t)n * P_) * WORDS + (size_t)gl * 4;
        float num0 = 0.f, num1 = 0.f, num2 = 0.f, num3 = 0.f;
        int   den0 = 0, den1 = 0, den2 = 0, den3 = 0;
        #pragma unroll
        for (int p = 0; p < P_; ++p) {
            float w8 = ioumax[n * P_ + p];
            const u64* wp = base + (size_t)p * WORDS;
            u64 w0 = wp[0], w1 = wp[1], w2 = wp[2], w3 = wp[3];
            int b0 = (int)((w0 >> lane) & 1ull);
            int b1 = (int)((w1 >> lane) & 1ull);
            int b2 = (int)((w2 >> lane) & 1ull);
            int b3 = (int)((w3 >> lane) & 1ull);
            num0 += b0 ? w8 : 0.0f;  den0 += b0;
            num1 += b1 ? w8 : 0.0f;  den1 += b1;
            num2 += b2 ? w8 : 0.0f;  den2 += b2;
            num3 += b3 ? w8 : 0.0f;  den3 += b3;
        }
        float4 o;
        o.x = den0 ? num0 / (float)den0 : 0.0f;
        o.y = den1 ? num1 / (float)den1 : 0.0f;
        o.z = den2 ? num2 / (float)den2 : 0.0f;
        o.w = den3 ? num3 / (float)den3 : 0.0f;
        reinterpret_cast<float4*>(out)[(size_t)g * 64 + lane] = o;
    }
}

extern "C" void kernel_launch(void* const* d_in, const int* in_sizes, int n_in,
                              void* d_out, int out_size, void* d_ws, size_t ws_size,
                              hipStream_t stream) {
    const float* gp = (const float*)d_in[0];   // (N,P,H,W)
    const float* gt = (const float*)d_in[1];   // (N,T,H,W)
    float* out = (float*)d_out;                // (N,H,W)

    char* ws = (char*)d_ws;
    u64*   packed_p = (u64*)ws;                                      // 256*2304*8 = 4,718,592 B
    u64*   packed_t = (u64*)(ws + (size_t)N_ * P_ * WORDS * 8);      // 128*2304*8 = 2,359,296 B
    float* inter    = (float*)(ws + (size_t)(N_ * P_ + N_ * T_) * WORDS * 8);
    float* area_p   = inter + N_ * P_ * T_;
    float* area_t   = area_p + N_ * P_;
    float* ioumax   = area_t + N_ * T_;

    const int pred_groups = N_ * P_ * HW / 256;   // 147456
    const int true_groups = N_ * T_ * HW / 256;   // 73728

    hipLaunchKernelGGL(pack_kernel, dim3(2048), dim3(256), 0, stream, gp, packed_p, pred_groups);
    hipLaunchKernelGGL(pack_kernel, dim3(1024), dim3(256), 0, stream, gt, packed_t, true_groups);
    hipLaunchKernelGGL(inter_kernel, dim3(N_ * P_), dim3(256), 0, stream,
                       packed_p, packed_t, inter, area_p, area_t);
    hipLaunchKernelGGL(ioumax_kernel, dim3(1), dim3(256), 0, stream,
                       inter, area_p, area_t, ioumax);
    hipLaunchKernelGGL(score_kernel, dim3(1152), dim3(256), 0, stream,
                       packed_p, ioumax, out);
}

// Round 2
// 78.957 us; speedup vs baseline: 2.0313x; 2.0313x over previous
//
#include <hip/hip_runtime.h>
#include <cstdint>
#include <cstddef>

typedef unsigned long long u64;

// Problem constants (N,P,T,H,W) = (8,32,16,384,384)
constexpr int N_  = 8;
constexpr int P_  = 32;
constexpr int T_  = 16;
constexpr int HW  = 384 * 384;        // 147456 pixels per mask
constexpr int WORDS = HW / 64;        // 2304 u64 words per mask
constexpr int GPN = HW / 256;         // 576 256-pixel groups per image

// ---------------------------------------------------------------------------
// Pack float {0,1} masks into bits. One wave handles 256 consecutive pixels:
// lane l loads float4 at pixel g*256 + 4l; bit layout: word[g*4+j] bit l =
// pixel (g*256 + 4l + j). Consumers use the identical layout.
// ---------------------------------------------------------------------------
__global__ void pack_kernel(const float* __restrict__ src, u64* __restrict__ dst,
                            int ngroups) {
    int wave   = (blockIdx.x * blockDim.x + threadIdx.x) >> 6;
    int lane   = threadIdx.x & 63;
    int nwaves = (gridDim.x * blockDim.x) >> 6;
    for (int g = wave; g < ngroups; g += nwaves) {
        float4 v = reinterpret_cast<const float4*>(src)[(size_t)g * 64 + lane];
        u64 b0 = __ballot(v.x != 0.0f);
        u64 b1 = __ballot(v.y != 0.0f);
        u64 b2 = __ballot(v.z != 0.0f);
        u64 b3 = __ballot(v.w != 0.0f);
        if (lane == 0) {
            u64* d = dst + (size_t)g * 4;
            d[0] = b0; d[1] = b1; d[2] = b2; d[3] = b3;
        }
    }
}

// Block-wide integer sum reduction (256 threads = 4 waves). Result on all threads.
__device__ inline int block_reduce_sum(int v) {
    __shared__ int buf[4];
    #pragma unroll
    for (int o = 32; o >= 1; o >>= 1) v += __shfl_down(v, o, 64);
    __syncthreads();                       // protect buf from a previous call
    if ((threadIdx.x & 63) == 0) buf[threadIdx.x >> 6] = v;
    __syncthreads();
    return buf[0] + buf[1] + buf[2] + buf[3];
}

// ---------------------------------------------------------------------------
// One 256-thread block per (n,p): holds its 9 pred words in registers, loops
// over t computing popcount(pred & true). Also emits area_p; the p==0 blocks
// additionally emit area_t.
// ---------------------------------------------------------------------------
__global__ __launch_bounds__(256)
void inter_kernel(const u64* __restrict__ pp, const u64* __restrict__ pt,
                  float* __restrict__ inter, float* __restrict__ area_p,
                  float* __restrict__ area_t) {
    const int np = blockIdx.x;            // n*P + p
    const int n  = np >> 5;
    const int p  = np & 31;
    const int tid = threadIdx.x;

    const u64* pw = pp + (size_t)np * WORDS;
    u64 a[9];
    #pragma unroll
    for (int k = 0; k < 9; ++k) a[k] = pw[tid + 256 * k];

    int my_area = 0;
    #pragma unroll
    for (int k = 0; k < 9; ++k) my_area += __popcll(a[k]);
    int ap = block_reduce_sum(my_area);
    if (tid == 0) area_p[np] = (float)ap;

    for (int t = 0; t < T_; ++t) {
        const u64* tw = pt + ((size_t)(n * T_ + t)) * WORDS;
        int s = 0, st = 0;
        #pragma unroll
        for (int k = 0; k < 9; ++k) {
            u64 w = tw[tid + 256 * k];
            s += __popcll(a[k] & w);
            if (p == 0) st += __popcll(w);
        }
        int is = block_reduce_sum(s);
        if (tid == 0) inter[(size_t)np * T_ + t] = (float)is;
        if (p == 0) {                     // block-uniform branch: syncs are safe
            int at = block_reduce_sum(st);
            if (tid == 0) area_t[n * T_ + t] = (float)at;
        }
    }
}

// ---------------------------------------------------------------------------
// Per-pixel score, ioumax fused. One block = 4 pixel-groups (1024 pixels) of
// one image (GPN % 4 == 0, so all 4 groups share n). Stage the 32 masks' words
// for these groups into LDS with coalesced loads; each wave then consumes its
// group's words via conflict-free LDS broadcast reads.
// ---------------------------------------------------------------------------
__global__ __launch_bounds__(256)
void score_kernel(const u64* __restrict__ pm,
                  const float* __restrict__ inter,
                  const float* __restrict__ area_p,
                  const float* __restrict__ area_t,
                  float* __restrict__ out) {
    __shared__ u64   wlds[P_][16];     // [p][gl_local*4 + j], 4 KB
    __shared__ float iou[P_];

    const int tid  = threadIdx.x;
    const int lane = tid & 63;
    const int wv   = tid >> 6;         // which of the 4 groups
    const int gblk = blockIdx.x * 4;   // global group id (n-major over n*GPN)
    const int n    = gblk / GPN;
    const int gl0  = gblk - n * GPN;

    // Stage 4 KB: thread tid loads 16 B (two u64) — 8 lanes per 128 B segment.
    {
        int p = tid >> 3, k = tid & 7;
        const u64* s = pm + ((size_t)(n * P_ + p)) * WORDS + (size_t)gl0 * 4 + 2 * k;
        ulonglong2 v = *reinterpret_cast<const ulonglong2*>(s);
        *reinterpret_cast<ulonglong2*>(&wlds[p][2 * k]) = v;
    }

    // iou_max for image n (32 threads, reads tiny L2-hot buffers)
    if (tid < P_) {
        float ap = area_p[n * P_ + tid];
        float best = 0.0f;
        #pragma unroll
        for (int t = 0; t < T_; ++t) {
            float it = inter[(size_t)(n * P_ + tid) * T_ + t];
            float u  = ap + area_t[n * T_ + t] - it;
            best = fmaxf(best, (u > 0.0f) ? it / u : 0.0f);
        }
        iou[tid] = best;
    }
    __syncthreads();

    float num0 = 0.f, num1 = 0.f, num2 = 0.f, num3 = 0.f;
    int   den0 = 0, den1 = 0, den2 = 0, den3 = 0;
    #pragma unroll
    for (int p = 0; p < P_; ++p) {
        float w8 = iou[p];
        u64 w0 = wlds[p][wv * 4 + 0];   // uniform addr per wave -> broadcast
        u64 w1 = wlds[p][wv * 4 + 1];
        u64 w2 = wlds[p][wv * 4 + 2];
        u64 w3 = wlds[p][wv * 4 + 3];
        unsigned b0 = (unsigned)(w0 >> lane) & 1u;
        unsigned b1 = (unsigned)(w1 >> lane) & 1u;
        unsigned b2 = (unsigned)(w2 >> lane) & 1u;
        unsigned b3 = (unsigned)(w3 >> lane) & 1u;
        num0 += b0 ? w8 : 0.0f;  den0 += b0;
        num1 += b1 ? w8 : 0.0f;  den1 += b1;
        num2 += b2 ? w8 : 0.0f;  den2 += b2;
        num3 += b3 ? w8 : 0.0f;  den3 += b3;
    }

    float4 o;
    o.x = den0 ? num0 / (float)den0 : 0.0f;
    o.y = den1 ? num1 / (float)den1 : 0.0f;
    o.z = den2 ? num2 / (float)den2 : 0.0f;
    o.w = den3 ? num3 / (float)den3 : 0.0f;
    reinterpret_cast<float4*>(out)[(size_t)(gblk + wv) * 64 + lane] = o;
}

extern "C" void kernel_launch(void* const* d_in, const int* in_sizes, int n_in,
                              void* d_out, int out_size, void* d_ws, size_t ws_size,
                              hipStream_t stream) {
    const float* gp = (const float*)d_in[0];   // (N,P,H,W)
    const float* gt = (const float*)d_in[1];   // (N,T,H,W)
    float* out = (float*)d_out;                // (N,H,W)

    char* ws = (char*)d_ws;
    u64*   packed_p = (u64*)ws;                                      // 256*2304*8 = 4,718,592 B
    u64*   packed_t = (u64*)(ws + (size_t)N_ * P_ * WORDS * 8);      // 128*2304*8 = 2,359,296 B
    float* inter    = (float*)(ws + (size_t)(N_ * P_ + N_ * T_) * WORDS * 8);
    float* area_p   = inter + N_ * P_ * T_;
    float* area_t   = area_p + N_ * P_;

    const int pred_groups = N_ * P_ * HW / 256;   // 147456
    const int true_groups = N_ * T_ * HW / 256;   // 73728

    hipLaunchKernelGGL(pack_kernel, dim3(2048), dim3(256), 0, stream, gp, packed_p, pred_groups);
    hipLaunchKernelGGL(pack_kernel, dim3(1024), dim3(256), 0, stream, gt, packed_t, true_groups);
    hipLaunchKernelGGL(inter_kernel, dim3(N_ * P_), dim3(256), 0, stream,
                       packed_p, packed_t, inter, area_p, area_t);
    hipLaunchKernelGGL(score_kernel, dim3(N_ * GPN / 4), dim3(256), 0, stream,
                       packed_p, inter, area_p, area_t, out);
}